// Round 1
// baseline (5262.843 us; speedup 1.0000x reference)
//
#include <hip/hip_runtime.h>
#include <hip/hip_bf16.h>
#include <cstddef>

// Problem constants (Swin shifted-window attention)
#define DIMS   192
#define HD     32
#define HEADS  6
#define HH     56
#define WW     56
#define WS     7
#define SS     3
#define NH     8
#define NW     8
#define NWIN   64
#define LTOK   49
#define BATCH  32
#define SCALE  0.17677669529663687f   // 1/sqrt(32)

// ---------------------------------------------------------------------------
// Kernel 1: per (window, head) fused QKV + attention.
// grid = BATCH*NWIN*HEADS = 12288 blocks, 256 threads.
// Writes attn_out[w][t][h][d] (fp32) to workspace.
// ---------------------------------------------------------------------------
__global__ __launch_bounds__(256) void swin_qkv_attn(
    const float* __restrict__ x,
    const float* __restrict__ w_qkv,
    const float* __restrict__ b_qkv,
    const float* __restrict__ pos_enc,
    float* __restrict__ attn_out)
{
    __shared__ __align__(16) float sX[LTOK * DIMS];   // 37632 B (aliased by sAtt)
    __shared__ __align__(16) float sQ[LTOK * HD];
    __shared__ __align__(16) float sK[LTOK * HD];
    __shared__ __align__(16) float sV[LTOK * HD];
    __shared__ int sReg[LTOK];

    const int blk = blockIdx.x;
    const int w   = blk / HEADS;          // window id 0..2047
    const int h   = blk - w * HEADS;      // head id
    const int b   = w >> 6;               // batch
    const int win = w & 63;
    const int nh  = win >> 3;
    const int nw  = win & 7;
    const int tid = threadIdx.x;

    // ---- Phase A: gather shifted window into LDS -------------------------
    for (int s = tid; s < LTOK * 48; s += 256) {
        int t  = s / 48;
        int c4 = s - t * 48;
        int ty = t / WS, tx = t - ty * WS;
        int sy = nh * WS + ty + SS; if (sy >= HH) sy -= HH;
        int sx = nw * WS + tx + SS; if (sx >= WW) sx -= WW;
        float4 v = *(const float4*)(x + ((size_t)b * (HH * WW) + sy * WW + sx) * DIMS + c4 * 4);
        *(float4*)(sX + t * DIMS + c4 * 4) = v;
    }
    if (tid < LTOK) {
        int ty = tid / WS, tx = tid - ty * WS;
        int hy = nh * WS + ty, hx = nw * WS + tx;
        int ry = hy < (HH - WS) ? 0 : (hy < (HH - SS) ? 1 : 2);
        int rx = hx < (WW - WS) ? 0 : (hx < (WW - SS) ? 1 : 2);
        sReg[tid] = ry * 3 + rx;
    }
    __syncthreads();

    // ---- Phase B: q,k,v = xw @ w_qkv.T + b -------------------------------
    // 8 groups of 32 lanes; each (kind,t) pair processed by one group,
    // lane d owns weight row (kind*192 + h*32 + d).
    {
        const int g = tid >> 5, d = tid & 31;
        for (int p = g; p < 3 * LTOK; p += 8) {
            int kind = p / LTOK;
            int t    = p - kind * LTOK;
            int row  = kind * DIMS + h * HD + d;
            const float4* wr = (const float4*)(w_qkv + (size_t)row * DIMS);
            const float4* xr = (const float4*)(sX + t * DIMS);
            float acc = b_qkv[row];
            #pragma unroll 8
            for (int k4 = 0; k4 < 48; ++k4) {
                float4 wv = wr[k4];
                float4 xv = xr[k4];
                acc += xv.x * wv.x + xv.y * wv.y + xv.z * wv.z + xv.w * wv.w;
            }
            float* dst = (kind == 0) ? sQ : ((kind == 1) ? sK : sV);
            dst[t * HD + d] = acc;
        }
    }
    __syncthreads();

    // ---- Phase C: scores + rel bias + mask -------------------------------
    float* sAtt = sX;  // alias: sX no longer needed
    const float* pe = pos_enc + h * (2 * WS - 1) * (2 * WS - 1);
    for (int s = tid; s < LTOK * LTOK; s += 256) {
        int i = s / LTOK, j = s - i * LTOK;
        float sc;
        if (sReg[i] != sReg[j]) {
            sc = -3.0e38f;
        } else {
            const float4* qi = (const float4*)(sQ + i * HD);
            const float4* kj = (const float4*)(sK + j * HD);
            float acc = 0.f;
            #pragma unroll
            for (int k4 = 0; k4 < 8; ++k4) {
                float4 a = qi[k4], c = kj[k4];
                acc += a.x * c.x + a.y * c.y + a.z * c.z + a.w * c.w;
            }
            int y1 = i / WS, x1 = i - y1 * WS;
            int y2 = j / WS, x2 = j - y2 * WS;
            int ridx = (y1 - y2 + WS - 1) * (2 * WS - 1) + (x1 - x2 + WS - 1);
            sc = acc * SCALE + pe[ridx];
        }
        sAtt[s] = sc;
    }
    __syncthreads();

    // ---- softmax over rows (49 rows, one thread each) --------------------
    if (tid < LTOK) {
        float* row = sAtt + tid * LTOK;
        float m = row[0];
        for (int j = 1; j < LTOK; ++j) m = fmaxf(m, row[j]);
        float sum = 0.f;
        for (int j = 0; j < LTOK; ++j) { float e = __expf(row[j] - m); row[j] = e; sum += e; }
        float inv = 1.0f / sum;
        for (int j = 0; j < LTOK; ++j) row[j] *= inv;
    }
    __syncthreads();

    // ---- PV + write attn_out[w][t][h][d] ---------------------------------
    for (int s = tid; s < LTOK * HD; s += 256) {
        int i = s / HD, d2 = s - i * HD;
        float acc = 0.f;
        #pragma unroll 7
        for (int j = 0; j < LTOK; ++j) acc += sAtt[i * LTOK + j] * sV[j * HD + d2];
        attn_out[(((size_t)w * LTOK + i) * HEADS + h) * HD + d2] = acc;
    }
}

// ---------------------------------------------------------------------------
// Kernel 2: output projection + un-window/un-shift scatter.
// grid = 2048 blocks (one window), 192 threads (lane = output column).
// ---------------------------------------------------------------------------
__global__ __launch_bounds__(192) void swin_proj(
    const float* __restrict__ attn_out,
    const float* __restrict__ w_out,
    const float* __restrict__ b_out,
    float* __restrict__ out)
{
    __shared__ __align__(16) float sA[LTOK * DIMS];

    const int w   = blockIdx.x;
    const int b   = w >> 6;
    const int win = w & 63;
    const int nh  = win >> 3;
    const int nw  = win & 7;
    const int tid = threadIdx.x;   // = output column o, 0..191

    const float4* src = (const float4*)(attn_out + (size_t)w * LTOK * DIMS);
    for (int s = tid; s < LTOK * 48; s += 192)
        ((float4*)sA)[s] = src[s];
    __syncthreads();

    float acc[LTOK];
    #pragma unroll
    for (int t = 0; t < LTOK; ++t) acc[t] = 0.f;

    const float* wrow = w_out + (size_t)tid * DIMS;
    for (int kc = 0; kc < DIMS; kc += 64) {
        float4 wv[16];
        #pragma unroll
        for (int j = 0; j < 16; ++j) wv[j] = *(const float4*)(wrow + kc + j * 4);
        for (int t = 0; t < LTOK; ++t) {
            const float4* xr = (const float4*)(sA + t * DIMS + kc);
            float a = 0.f;
            #pragma unroll
            for (int j = 0; j < 16; ++j) {
                float4 xv = xr[j];
                a += xv.x * wv[j].x + xv.y * wv[j].y + xv.z * wv[j].z + xv.w * wv[j].w;
            }
            acc[t] += a;
        }
    }

    const float bo = b_out[tid];
    for (int t = 0; t < LTOK; ++t) {
        int ty = t / WS, tx = t - ty * WS;
        int dy = nh * WS + ty + SS; if (dy >= HH) dy -= HH;
        int dx = nw * WS + tx + SS; if (dx >= WW) dx -= WW;
        out[((size_t)b * (HH * WW) + dy * WW + dx) * DIMS + tid] = acc[t] + bo;
    }
}

// ---------------------------------------------------------------------------
extern "C" void kernel_launch(void* const* d_in, const int* in_sizes, int n_in,
                              void* d_out, int out_size, void* d_ws, size_t ws_size,
                              hipStream_t stream) {
    const float* x       = (const float*)d_in[0];
    const float* w_qkv   = (const float*)d_in[1];
    const float* b_qkv   = (const float*)d_in[2];
    const float* w_out   = (const float*)d_in[3];
    const float* b_out   = (const float*)d_in[4];
    const float* pos_enc = (const float*)d_in[5];
    float* out  = (float*)d_out;
    float* attn = (float*)d_ws;   // 2048*49*192*4 = 77,070,336 B

    swin_qkv_attn<<<dim3(BATCH * NWIN * HEADS), dim3(256), 0, stream>>>(
        x, w_qkv, b_qkv, pos_enc, attn);
    swin_proj<<<dim3(BATCH * NWIN), dim3(192), 0, stream>>>(
        attn, w_out, b_out, out);
}

// Round 2
// 349.325 us; speedup vs baseline: 15.0658x; 15.0658x over previous
//
#include <hip/hip_runtime.h>
#include <hip/hip_bf16.h>
#include <cstddef>

typedef _Float16 half_t;
typedef _Float16 half8  __attribute__((ext_vector_type(8)));
typedef _Float16 half4v __attribute__((ext_vector_type(4)));
typedef float    f32x4  __attribute__((ext_vector_type(4)));

#define SCALE 0.17677669529663687f   // 1/sqrt(32)

// ---------------------------------------------------------------------------
// Convert weights fp32 -> fp16 into workspace.
// ---------------------------------------------------------------------------
__global__ __launch_bounds__(256) void convert_w(
    const float* __restrict__ w_qkv, const float* __restrict__ w_out,
    half_t* __restrict__ wq, half_t* __restrict__ wo)
{
    int i = blockIdx.x * 256 + threadIdx.x;
    if (i < 576 * 192) {
        wq[i] = (half_t)w_qkv[i];
    } else {
        int j = i - 576 * 192;
        if (j < 192 * 192) wo[j] = (half_t)w_out[j];
    }
}

// ---------------------------------------------------------------------------
// Kernel A: per-window fused QKV + attention (fp16 MFMA).
// grid = 2048 (one block per window), 512 threads = 8 waves.
// Waves split: ti = wave&3 (16-token row tile), hf = wave>>2 (col half / head).
// Writes attn16[w][t][h*32+d] fp16 to workspace.
// ---------------------------------------------------------------------------
__global__ __launch_bounds__(512, 4) void swin_attn(
    const float*  __restrict__ x,
    const half_t* __restrict__ wqkv16,
    const float*  __restrict__ b_qkv,
    const float*  __restrict__ pos_enc,
    half_t* __restrict__ attn16)
{
    __shared__ half_t sX[64][200];      // tokens x dim, fp16, rows 49..63 zero
    __shared__ half_t sQ[2][64][40];    // per head-in-pair: tok x 32 (+pad)
    __shared__ half_t sK[2][64][40];
    __shared__ half_t sVT[2][32][72];   // transposed: dim x tok (+pad)
    __shared__ half_t sP[2][64][72];    // softmax probs, tok x tok (+pad)
    __shared__ int    sReg[64];

    const int w    = blockIdx.x;
    const int b    = w >> 6, win = w & 63, nh = win >> 3, nw = win & 7;
    const int tid  = threadIdx.x;
    const int wave = tid >> 6, lane = tid & 63;
    const int c    = lane & 15, g = lane >> 4;
    const int ti   = wave & 3;
    const int hf   = wave >> 2;

    // ---- gather shifted window, convert to fp16 --------------------------
    for (int s = tid; s < 49 * 48; s += 512) {
        int t = s / 48, c4 = s - t * 48;
        int ty = t / 7, tx = t - ty * 7;
        int sy = nh * 7 + ty + 3; if (sy >= 56) sy -= 56;
        int sx = nw * 7 + tx + 3; if (sx >= 56) sx -= 56;
        float4 v = *(const float4*)(x + ((size_t)b * 3136 + sy * 56 + sx) * 192 + c4 * 4);
        half4v h = { (half_t)v.x, (half_t)v.y, (half_t)v.z, (half_t)v.w };
        *(half4v*)&sX[t][c4 * 4] = h;
    }
    for (int s = tid; s < 15 * 48; s += 512) {
        int t = 49 + s / 48, c4 = s - (s / 48) * 48;
        half4v h = {(half_t)0.f, (half_t)0.f, (half_t)0.f, (half_t)0.f};
        *(half4v*)&sX[t][c4 * 4] = h;
    }
    if (tid < 64) {
        int r = 0;
        if (tid < 49) {
            int ty = tid / 7, tx = tid - ty * 7;
            int hy = nh * 7 + ty, hx = nw * 7 + tx;
            int ry = hy < 49 ? 0 : (hy < 53 ? 1 : 2);
            int rx = hx < 49 ? 0 : (hx < 53 ? 1 : 2);
            r = ry * 3 + rx;
        }
        sReg[tid] = r;
    }
    __syncthreads();

    for (int pp = 0; pp < 3; ++pp) {
        // ---- QKV slice for heads {2pp, 2pp+1} ----------------------------
        // col-tile ct (0..11): cc=ct>>1 -> kind=cc>>1, hh=cc&1; d = (ct&1)*16+c
        {
            f32x4 acc[6];
            #pragma unroll
            for (int q = 0; q < 6; ++q) acc[q] = {0.f, 0.f, 0.f, 0.f};
            #pragma unroll
            for (int ks = 0; ks < 6; ++ks) {
                half8 aF = *(const half8*)&sX[16 * ti + c][ks * 32 + g * 8];
                #pragma unroll
                for (int q = 0; q < 6; ++q) {
                    int ct = 6 * hf + q;
                    int cc = ct >> 1, kind = cc >> 1, hh = cc & 1;
                    int d  = ((ct & 1) << 4) + c;
                    int feat = kind * 192 + (2 * pp + hh) * 32 + d;
                    half8 bF = *(const half8*)(wqkv16 + feat * 192 + ks * 32 + g * 8);
                    acc[q] = __builtin_amdgcn_mfma_f32_16x16x32_f16(aF, bF, acc[q], 0, 0, 0);
                }
            }
            #pragma unroll
            for (int q = 0; q < 6; ++q) {
                int ct = 6 * hf + q;
                int cc = ct >> 1, kind = cc >> 1, hh = cc & 1;
                int d  = ((ct & 1) << 4) + c;
                int feat = kind * 192 + (2 * pp + hh) * 32 + d;
                float bias = b_qkv[feat];
                #pragma unroll
                for (int r = 0; r < 4; ++r) {
                    int tok = 16 * ti + g * 4 + r;
                    half_t val = (half_t)(acc[q][r] + bias);
                    if (kind == 0)      sQ[hh][tok][d]  = val;
                    else if (kind == 1) sK[hh][tok][d]  = val;
                    else                sVT[hh][d][tok] = val;
                }
            }
        }
        __syncthreads();

        // ---- attention: wave handles head hh = hf, row-tile ti -----------
        {
            const int hh = hf;
            const int h  = 2 * pp + hh;
            f32x4 st[4];
            half8 aQ = *(const half8*)&sQ[hh][16 * ti + c][g * 8];
            #pragma unroll
            for (int tj = 0; tj < 4; ++tj) {
                half8 bK = *(const half8*)&sK[hh][16 * tj + c][g * 8];
                f32x4 z = {0.f, 0.f, 0.f, 0.f};
                st[tj] = __builtin_amdgcn_mfma_f32_16x16x32_f16(aQ, bK, z, 0, 0, 0);
            }
            // scale + relative position bias + shift mask
            const float* pe = pos_enc + h * 169;
            #pragma unroll
            for (int tj = 0; tj < 4; ++tj) {
                int j = 16 * tj + c;
                #pragma unroll
                for (int r = 0; r < 4; ++r) {
                    int i = 16 * ti + g * 4 + r;
                    float sc = -3.0e38f;
                    if (j < 49 && i < 49 && sReg[i] == sReg[j]) {
                        int y1 = i / 7, x1 = i - y1 * 7;
                        int y2 = j / 7, x2 = j - y2 * 7;
                        sc = st[tj][r] * SCALE + pe[(y1 - y2 + 6) * 13 + (x1 - x2 + 6)];
                    }
                    st[tj][r] = sc;
                }
            }
            // in-register softmax: row = 16ti + g*4 + r; cols across 16 lanes x 4 tj
            #pragma unroll
            for (int r = 0; r < 4; ++r) {
                float m = fmaxf(fmaxf(st[0][r], st[1][r]), fmaxf(st[2][r], st[3][r]));
                m = fmaxf(m, __shfl_xor(m, 1));
                m = fmaxf(m, __shfl_xor(m, 2));
                m = fmaxf(m, __shfl_xor(m, 4));
                m = fmaxf(m, __shfl_xor(m, 8));
                float ssum = 0.f;
                #pragma unroll
                for (int tj = 0; tj < 4; ++tj) {
                    float e = __expf(st[tj][r] - m);
                    st[tj][r] = e;
                    ssum += e;
                }
                ssum += __shfl_xor(ssum, 1);
                ssum += __shfl_xor(ssum, 2);
                ssum += __shfl_xor(ssum, 4);
                ssum += __shfl_xor(ssum, 8);
                float inv = 1.0f / ssum;
                #pragma unroll
                for (int tj = 0; tj < 4; ++tj)
                    sP[hh][16 * ti + g * 4 + r][16 * tj + c] = (half_t)(st[tj][r] * inv);
            }
            // PV: wave reads its own sP rows -> no barrier needed
            f32x4 o0 = {0.f, 0.f, 0.f, 0.f}, o1 = {0.f, 0.f, 0.f, 0.f};
            #pragma unroll
            for (int ks = 0; ks < 2; ++ks) {
                half8 aP  = *(const half8*)&sP[hh][16 * ti + c][ks * 32 + g * 8];
                half8 bV0 = *(const half8*)&sVT[hh][c][ks * 32 + g * 8];
                half8 bV1 = *(const half8*)&sVT[hh][16 + c][ks * 32 + g * 8];
                o0 = __builtin_amdgcn_mfma_f32_16x16x32_f16(aP, bV0, o0, 0, 0, 0);
                o1 = __builtin_amdgcn_mfma_f32_16x16x32_f16(aP, bV1, o1, 0, 0, 0);
            }
            #pragma unroll
            for (int r = 0; r < 4; ++r) {
                int tok = 16 * ti + g * 4 + r;
                if (tok < 49) {
                    size_t base = ((size_t)w * 49 + tok) * 192 + h * 32;
                    attn16[base + c]      = (half_t)o0[r];
                    attn16[base + 16 + c] = (half_t)o1[r];
                }
            }
        }
        __syncthreads();
    }
}

// ---------------------------------------------------------------------------
// Kernel B: out-projection (fp16 MFMA) + un-shift scatter, fp32 output.
// grid = 2048 (one block per window), 256 threads = 4 waves (wave = row tile).
// ---------------------------------------------------------------------------
__global__ __launch_bounds__(256, 4) void swin_proj16(
    const half_t* __restrict__ attn16,
    const half_t* __restrict__ wout16,
    const float*  __restrict__ b_out,
    float* __restrict__ out)
{
    __shared__ half_t sA[64][200];

    const int w    = blockIdx.x;
    const int b    = w >> 6, win = w & 63, nh = win >> 3, nw = win & 7;
    const int tid  = threadIdx.x;
    const int lane = tid & 63;
    const int c    = lane & 15, g = lane >> 4;
    const int ti   = tid >> 6;

    for (int s = tid; s < 49 * 24; s += 256) {
        int t = s / 24, c8 = s - t * 24;
        *(half8*)&sA[t][c8 * 8] = *(const half8*)(attn16 + ((size_t)w * 49 + t) * 192 + c8 * 8);
    }
    for (int s = tid; s < 15 * 24; s += 256) {
        int t = 49 + s / 24, c8 = s - (s / 24) * 24;
        half8 z = {(half_t)0.f, (half_t)0.f, (half_t)0.f, (half_t)0.f,
                   (half_t)0.f, (half_t)0.f, (half_t)0.f, (half_t)0.f};
        *(half8*)&sA[t][c8 * 8] = z;
    }
    __syncthreads();

    f32x4 acc[12];
    #pragma unroll
    for (int ct = 0; ct < 12; ++ct) acc[ct] = {0.f, 0.f, 0.f, 0.f};

    #pragma unroll
    for (int ks = 0; ks < 6; ++ks) {
        half8 aF = *(const half8*)&sA[16 * ti + c][ks * 32 + g * 8];
        #pragma unroll
        for (int ct = 0; ct < 12; ++ct) {
            int o = 16 * ct + c;
            half8 bF = *(const half8*)(wout16 + o * 192 + ks * 32 + g * 8);
            acc[ct] = __builtin_amdgcn_mfma_f32_16x16x32_f16(aF, bF, acc[ct], 0, 0, 0);
        }
    }

    #pragma unroll
    for (int r = 0; r < 4; ++r) {
        int tok = 16 * ti + g * 4 + r;
        if (tok < 49) {
            int ty = tok / 7, tx = tok - ty * 7;
            int dy = nh * 7 + ty + 3; if (dy >= 56) dy -= 56;
            int dx = nw * 7 + tx + 3; if (dx >= 56) dx -= 56;
            float* op = out + ((size_t)b * 3136 + dy * 56 + dx) * 192;
            #pragma unroll
            for (int ct = 0; ct < 12; ++ct)
                op[16 * ct + c] = acc[ct][r] + b_out[16 * ct + c];
        }
    }
}

// ---------------------------------------------------------------------------
extern "C" void kernel_launch(void* const* d_in, const int* in_sizes, int n_in,
                              void* d_out, int out_size, void* d_ws, size_t ws_size,
                              hipStream_t stream) {
    const float* x       = (const float*)d_in[0];
    const float* w_qkv   = (const float*)d_in[1];
    const float* b_qkv   = (const float*)d_in[2];
    const float* w_out   = (const float*)d_in[3];
    const float* b_out   = (const float*)d_in[4];
    const float* pos_enc = (const float*)d_in[5];
    float* out = (float*)d_out;

    // workspace layout (bytes):
    //   [0, 221184)           wqkv16: 576x192 fp16
    //   [221184, 294912)      wout16: 192x192 fp16
    //   [294912, 38830080)    attn16: 2048x49x192 fp16
    half_t* wq16   = (half_t*)d_ws;
    half_t* wo16   = (half_t*)((char*)d_ws + 221184);
    half_t* attn16 = (half_t*)((char*)d_ws + 294912);

    convert_w<<<dim3(576), dim3(256), 0, stream>>>(w_qkv, w_out, wq16, wo16);
    swin_attn<<<dim3(2048), dim3(512), 0, stream>>>(x, wq16, b_qkv, pos_enc, attn16);
    swin_proj16<<<dim3(2048), dim3(256), 0, stream>>>(attn16, wo16, b_out, out);
}

// Round 3
// 330.915 us; speedup vs baseline: 15.9039x; 1.0556x over previous
//
#include <hip/hip_runtime.h>
#include <hip/hip_bf16.h>
#include <cstddef>

typedef _Float16 half_t;
typedef _Float16 half8  __attribute__((ext_vector_type(8)));
typedef _Float16 half4v __attribute__((ext_vector_type(4)));
typedef _Float16 half2v __attribute__((ext_vector_type(2)));
typedef float    f32x4  __attribute__((ext_vector_type(4)));

#define SCALE 0.17677669529663687f   // 1/sqrt(32)

// ---------------------------------------------------------------------------
// Convert weights fp32 -> fp16 into workspace.
// ---------------------------------------------------------------------------
__global__ __launch_bounds__(256) void convert_w(
    const float* __restrict__ w_qkv, const float* __restrict__ w_out,
    half_t* __restrict__ wq, half_t* __restrict__ wo)
{
    int i = blockIdx.x * 256 + threadIdx.x;
    if (i < 576 * 192) {
        wq[i] = (half_t)w_qkv[i];
    } else {
        int j = i - 576 * 192;
        if (j < 192 * 192) wo[j] = (half_t)w_out[j];
    }
}

// ---------------------------------------------------------------------------
// Fused kernel: gather+shift -> QKV (fp16 MFMA) -> attention (S^T form,
// register-resident P) -> out-projection -> un-shift scatter.
// grid = 2048 (one block per window), 512 threads = 8 waves.
// Wave split: ti = wave&3 (16-token row tile), hf = wave>>2 (col half/head).
// ---------------------------------------------------------------------------
__global__ __launch_bounds__(512, 4) void swin_fused(
    const float*  __restrict__ x,
    const half_t* __restrict__ wqkv16,
    const float*  __restrict__ b_qkv,
    const float*  __restrict__ pos_enc,
    const half_t* __restrict__ wout16,
    const float*  __restrict__ b_out,
    float* __restrict__ out)
{
    __shared__ half_t sQ[2][64][34];                 // [head-in-pair][tok][d]
    __shared__ half_t sK[2][64][34];
    __shared__ __align__(16) half_t sVT[2][32][72];  // [head-in-pair][d][tok]
    __shared__ __align__(16) half_t sA[64][200];     // attn output [tok][dim]
    __shared__ float  sBias[6 * 169];                // rel-pos bias per head
    __shared__ int    sReg[64];                      // shift-mask region id

    const int w    = blockIdx.x;
    const int b    = w >> 6, win = w & 63, nh = win >> 3, nw = win & 7;
    const int tid  = threadIdx.x;
    const int wave = tid >> 6, lane = tid & 63;
    const int c    = lane & 15, g = lane >> 4;
    const int ti   = wave & 3, hf = wave >> 2;
    const int i_tok = 16 * ti + c;   // this lane's token row (A-frag row / S^T col)

    // ---- X A-fragments straight to registers (shifted-window gather) -----
    half8 xf[6];
    if (i_tok < 49) {
        int ty = i_tok / 7, tx = i_tok - ty * 7;
        int sy = nh * 7 + ty + 3; if (sy >= 56) sy -= 56;
        int sx = nw * 7 + tx + 3; if (sx >= 56) sx -= 56;
        const float* xrow = x + ((size_t)b * 3136 + sy * 56 + sx) * 192 + g * 8;
        #pragma unroll
        for (int ks = 0; ks < 6; ++ks) {
            float4 v0 = *(const float4*)(xrow + ks * 32);
            float4 v1 = *(const float4*)(xrow + ks * 32 + 4);
            xf[ks] = (half8){(half_t)v0.x, (half_t)v0.y, (half_t)v0.z, (half_t)v0.w,
                             (half_t)v1.x, (half_t)v1.y, (half_t)v1.z, (half_t)v1.w};
        }
    } else {
        #pragma unroll
        for (int ks = 0; ks < 6; ++ks)
            xf[ks] = (half8){(half_t)0.f, (half_t)0.f, (half_t)0.f, (half_t)0.f,
                             (half_t)0.f, (half_t)0.f, (half_t)0.f, (half_t)0.f};
    }

    // ---- bias table + region ids into LDS --------------------------------
    for (int s = tid; s < 6 * 169; s += 512) sBias[s] = pos_enc[s];
    if (tid < 64) {
        int r = 0;
        if (tid < 49) {
            int ty = tid / 7, tx = tid - ty * 7;
            int hy = nh * 7 + ty, hx = nw * 7 + tx;
            int ry = hy < 49 ? 0 : (hy < 53 ? 1 : 2);
            int rx = hx < 49 ? 0 : (hx < 53 ? 1 : 2);
            r = ry * 3 + rx;
        }
        sReg[tid] = r;
    }
    __syncthreads();

    const int regI = sReg[i_tok];
    const int y1 = i_tok / 7, x1 = i_tok - y1 * 7;
    const bool iok = (i_tok < 49);

    for (int pp = 0; pp < 3; ++pp) {
        // ---- QKV slice for heads {2pp, 2pp+1} ----------------------------
        {
            f32x4 acc[6];
            #pragma unroll
            for (int q = 0; q < 6; ++q) acc[q] = (f32x4){0.f, 0.f, 0.f, 0.f};
            #pragma unroll
            for (int ks = 0; ks < 6; ++ks) {
                #pragma unroll
                for (int q = 0; q < 6; ++q) {
                    int ct = 6 * hf + q;
                    int cc = ct >> 1, kind = cc >> 1, hh = cc & 1;
                    int d  = ((ct & 1) << 4) + c;
                    int feat = kind * 192 + (2 * pp + hh) * 32 + d;
                    half8 bF = *(const half8*)(wqkv16 + (size_t)feat * 192 + ks * 32 + g * 8);
                    acc[q] = __builtin_amdgcn_mfma_f32_16x16x32_f16(xf[ks], bF, acc[q], 0, 0, 0);
                }
            }
            #pragma unroll
            for (int q = 0; q < 6; ++q) {
                int ct = 6 * hf + q;
                int cc = ct >> 1, kind = cc >> 1, hh = cc & 1;
                int d  = ((ct & 1) << 4) + c;
                int feat = kind * 192 + (2 * pp + hh) * 32 + d;
                float bias = b_qkv[feat];
                #pragma unroll
                for (int r = 0; r < 4; ++r) {
                    int tok = 16 * ti + g * 4 + r;
                    half_t val = (half_t)(acc[q][r] + bias);
                    if (kind == 0)      sQ[hh][tok][d]  = val;
                    else if (kind == 1) sK[hh][tok][d]  = val;
                    else                sVT[hh][d][tok] = val;
                }
            }
        }
        __syncthreads();

        // ---- attention: wave = (head hh=hf, Q-token tile ti) --------------
        {
            const int hh = hf;
            const int h  = 2 * pp + hh;
            // S^T = K * Q^T : A-frag = K rows (j), B-frag = Q rows (i)
            half8 qf = *(const half8*)&sQ[hh][i_tok][g * 8];
            f32x4 st[4];
            #pragma unroll
            for (int tj = 0; tj < 4; ++tj) {
                half8 kf = *(const half8*)&sK[hh][16 * tj + c][g * 8];
                f32x4 z = (f32x4){0.f, 0.f, 0.f, 0.f};
                st[tj] = __builtin_amdgcn_mfma_f32_16x16x32_f16(kf, qf, z, 0, 0, 0);
            }
            // scale + rel-pos bias + shift mask.
            // lane (c,g) holds S[row i_tok][col j=16tj+4g+r]
            const float* bh = sBias + h * 169;
            #pragma unroll
            for (int tj = 0; tj < 4; ++tj) {
                #pragma unroll
                for (int r = 0; r < 4; ++r) {
                    int j = 16 * tj + 4 * g + r;
                    float sc = -3.0e38f;
                    if (iok && j < 49 && regI == sReg[j]) {
                        int y2 = j / 7, x2 = j - y2 * 7;
                        sc = st[tj][r] * SCALE + bh[(y1 - y2 + 6) * 13 + (x1 - x2 + 6)];
                    }
                    st[tj][r] = sc;
                }
            }
            // softmax over the full row (16 in-register + lanes c, c^16, c^32, c^48)
            float m = st[0][0];
            #pragma unroll
            for (int tj = 0; tj < 4; ++tj)
                #pragma unroll
                for (int r = 0; r < 4; ++r) m = fmaxf(m, st[tj][r]);
            m = fmaxf(m, __shfl_xor(m, 16));
            m = fmaxf(m, __shfl_xor(m, 32));
            float sum = 0.f;
            #pragma unroll
            for (int tj = 0; tj < 4; ++tj)
                #pragma unroll
                for (int r = 0; r < 4; ++r) {
                    float e = __expf(st[tj][r] - m);
                    st[tj][r] = e;
                    sum += e;
                }
            sum += __shfl_xor(sum, 16);
            sum += __shfl_xor(sum, 32);
            float inv = 1.0f / sum;
            // P stays in registers: pa[tj] is directly the 16x16x16 B-fragment
            half4v pa[4];
            #pragma unroll
            for (int tj = 0; tj < 4; ++tj)
                pa[tj] = (half4v){(half_t)(st[tj][0] * inv), (half_t)(st[tj][1] * inv),
                                  (half_t)(st[tj][2] * inv), (half_t)(st[tj][3] * inv)};
            // PV: O^T = V^T * P^T with k=16 MFMAs (A from sVT, B from registers)
            f32x4 o0 = (f32x4){0.f, 0.f, 0.f, 0.f};
            f32x4 o1 = (f32x4){0.f, 0.f, 0.f, 0.f};
            #pragma unroll
            for (int tj = 0; tj < 4; ++tj) {
                half4v v0 = *(const half4v*)&sVT[hh][c][16 * tj + 4 * g];
                half4v v1 = *(const half4v*)&sVT[hh][16 + c][16 * tj + 4 * g];
                o0 = __builtin_amdgcn_mfma_f32_16x16x16f16(v0, pa[tj], o0, 0, 0, 0);
                o1 = __builtin_amdgcn_mfma_f32_16x16x16f16(v1, pa[tj], o1, 0, 0, 0);
            }
            // lane holds O[i_tok][d = 16dt + 4g + r] -> packed half2 stores
            #pragma unroll
            for (int rr = 0; rr < 2; ++rr) {
                *(half2v*)&sA[i_tok][h * 32 + 4 * g + 2 * rr] =
                    (half2v){(half_t)o0[2 * rr], (half_t)o0[2 * rr + 1]};
                *(half2v*)&sA[i_tok][h * 32 + 16 + 4 * g + 2 * rr] =
                    (half2v){(half_t)o1[2 * rr], (half_t)o1[2 * rr + 1]};
            }
        }
        __syncthreads();
    }

    // ---- out-projection + un-shift scatter -------------------------------
    {
        f32x4 pacc[6];
        float bo[6];
        #pragma unroll
        for (int q = 0; q < 6; ++q) {
            pacc[q] = (f32x4){0.f, 0.f, 0.f, 0.f};
            bo[q] = b_out[16 * (6 * hf + q) + c];
        }
        #pragma unroll
        for (int ks = 0; ks < 6; ++ks) {
            half8 aF = *(const half8*)&sA[i_tok][ks * 32 + g * 8];
            #pragma unroll
            for (int q = 0; q < 6; ++q) {
                int o = 16 * (6 * hf + q) + c;
                half8 bF = *(const half8*)(wout16 + (size_t)o * 192 + ks * 32 + g * 8);
                pacc[q] = __builtin_amdgcn_mfma_f32_16x16x32_f16(aF, bF, pacc[q], 0, 0, 0);
            }
        }
        #pragma unroll
        for (int r = 0; r < 4; ++r) {
            int tok = 16 * ti + g * 4 + r;
            if (tok < 49) {
                int ty = tok / 7, tx = tok - ty * 7;
                int dy = nh * 7 + ty + 3; if (dy >= 56) dy -= 56;
                int dx = nw * 7 + tx + 3; if (dx >= 56) dx -= 56;
                float* op = out + ((size_t)b * 3136 + dy * 56 + dx) * 192;
                #pragma unroll
                for (int q = 0; q < 6; ++q)
                    op[16 * (6 * hf + q) + c] = pacc[q][r] + bo[q];
            }
        }
    }
}

// ---------------------------------------------------------------------------
extern "C" void kernel_launch(void* const* d_in, const int* in_sizes, int n_in,
                              void* d_out, int out_size, void* d_ws, size_t ws_size,
                              hipStream_t stream) {
    const float* x       = (const float*)d_in[0];
    const float* w_qkv   = (const float*)d_in[1];
    const float* b_qkv   = (const float*)d_in[2];
    const float* w_out   = (const float*)d_in[3];
    const float* b_out   = (const float*)d_in[4];
    const float* pos_enc = (const float*)d_in[5];
    float* out = (float*)d_out;

    // workspace: [0, 221184) wqkv16 fp16; [221184, 294912) wout16 fp16
    half_t* wq16 = (half_t*)d_ws;
    half_t* wo16 = (half_t*)((char*)d_ws + 221184);

    convert_w<<<dim3(576), dim3(256), 0, stream>>>(w_qkv, w_out, wq16, wo16);
    swin_fused<<<dim3(2048), dim3(512), 0, stream>>>(
        x, wq16, b_qkv, pos_enc, wo16, b_out, out);
}